// Round 9
// baseline (123.885 us; speedup 1.0000x reference)
//
#include <hip/hip_runtime.h>

// Problem constants (nb=16, k=11, ps=10, with_padding=1, rgb 1x3x2048x2048 f32)
constexpr int H   = 2048;
constexpr int W   = 2048;
constexpr int NB  = 16;
constexpr int K   = 11;
constexpr int PS  = 10;
constexpr int PAD = (K - 1) / 2;                 // 5
constexpr int HO  = (H + 2 * PAD - K) / PS + 1;  // 205
constexpr int WO  = (W + 2 * PAD - K) / PS + 1;  // 205
constexpr int PSP = PS + 1;                      // 11
constexpr int OH  = HO * PSP;                    // 2255
constexpr int OW  = WO * PSP;                    // 2255

constexpr int TW  = 4;                       // 4x4 windows per block
constexpr int R   = (TW - 1) * PS + K;       // 41 rows needed
constexpr int NF4 = 11;                      // float4 slots/row: [gx0-3, gx0+41) covers cols 0..40
constexpr int LP  = NF4 * 4;                 // 44 floats LDS row pitch
constexpr int NSLOT = R * NF4;               // 451 float4 slots per channel (21.6 KB total)

typedef float floatx4 __attribute__((ext_vector_type(4)));

#if __has_builtin(__builtin_amdgcn_global_load_lds)
#define HAVE_GLL 1
typedef const __attribute__((address_space(1))) void* gas_ptr;
typedef __attribute__((address_space(3))) void* las_ptr;
#else
#define HAVE_GLL 0
#endif

// Integer binning, bit-equivalent to (int)(fl(fl(s/3))*0.0625f)  (proof R8).
__device__ __forceinline__ int bin_of(float s) {
    return (int)((unsigned)s / 48u);
}

// Kernel 1 (unchanged from R8): one block = 4x4 window tile; GLL staging for
// interior blocks, float4+sentinel for edges; 16 threads/window; packed-u64
// histogram; shfl_xor(16) reduce; first-tie-wins argmax; conditional sums.
__global__ __launch_bounds__(256) void window_kernel(const float* __restrict__ rgb,
                                                     float* __restrict__ val) {
    __shared__ float ls_r[R * LP];
    __shared__ float ls_g[R * LP];
    __shared__ float ls_b[R * LP];

    int tid = threadIdx.x;
    int wy0 = blockIdx.y * TW;
    int wx0 = blockIdx.x * TW;
    int gy0 = wy0 * PS - PAD;
    int gx0 = wx0 * PS - PAD;          // == 3 (mod 4) for every block
    int f0  = gx0 >> 2;                // floor div: 10*bx - 2

    const float* __restrict__ rp = rgb;
    const float* __restrict__ gp = rgb + H * W;
    const float* __restrict__ bp = rgb + 2 * H * W;

    bool interior = (blockIdx.x >= 1) && (blockIdx.x <= 50) &&
                    (blockIdx.y >= 1) && (blockIdx.y <= 50);

#if HAVE_GLL
    if (interior) {
        int wv = tid >> 6;
        #pragma unroll
        for (int k = 0; k < 2; ++k) {
            int s     = k * 256 + tid;
            int sbase = k * 256 + wv * 64;
            if (sbase < NSLOT && s < NSLOT) {
                int row = s / NF4, f = s - row * NF4;
                long go = (long)(gy0 + row) * W + ((f0 + f) << 2);
                __builtin_amdgcn_global_load_lds((gas_ptr)(rp + go),
                                                 (las_ptr)(ls_r + sbase * 4), 16, 0, 0);
                __builtin_amdgcn_global_load_lds((gas_ptr)(gp + go),
                                                 (las_ptr)(ls_g + sbase * 4), 16, 0, 0);
                __builtin_amdgcn_global_load_lds((gas_ptr)(bp + go),
                                                 (las_ptr)(ls_b + sbase * 4), 16, 0, 0);
            }
        }
    } else
#endif
    {
        const float4 SENT = make_float4(1.0e9f, 1.0e9f, 1.0e9f, 1.0e9f);
        for (int s = tid; s < NSLOT; s += 256) {
            int row = s / NF4;
            int f   = s - row * NF4;
            int y   = gy0 + row;
            int fg  = f0 + f;
            float4 r4 = SENT, g4 = SENT, b4 = SENT;
            if ((unsigned)y < (unsigned)H && (unsigned)fg < (unsigned)(W / 4)) {
                long o = (long)y * W + (fg << 2);
                r4 = *(const float4*)(rp + o);
                g4 = *(const float4*)(gp + o);
                b4 = *(const float4*)(bp + o);
            }
            int la = row * LP + (f << 2);
            *(float4*)(ls_r + la) = r4;
            *(float4*)(ls_g + la) = g4;
            *(float4*)(ls_b + la) = b4;
        }
    }
    __syncthreads();

    int wid = tid >> 4;
    int sub = tid & 15;
    int wly = wid >> 2, wlx = wid & 3;
    int wy = wy0 + wly, wx = wx0 + wlx;
    bool valid = (wy < HO) && (wx < WO);
    int base = (wly * PS) * LP + (wlx * PS) + 3;

    float cr[8], cg[8], cb[8];
    int   ci[8];
    unsigned long long lo = 0ull, hi = 0ull;
    #pragma unroll
    for (int t = 0; t < 8; ++t) {
        int p = sub + 16 * t;
        float r = 0.f, g = 0.f, b = 0.f;
        int idx = 1 << 28;
        if (p < K * K) {
            int j = p / K, i = p - j * K;
            int addr = base + j * LP + i;
            r = ls_r[addr]; g = ls_g[addr]; b = ls_b[addr];
            idx = bin_of((r + g) + b);
        }
        cr[t] = r; cg[t] = g; cb[t] = b; ci[t] = idx;
        if ((unsigned)idx < 8u)       lo += 1ull << (idx * 8);
        else if ((unsigned)idx < 16u) hi += 1ull << ((idx - 8) * 8);
    }
    #pragma unroll
    for (int s = 1; s < 16; s <<= 1) {
        lo += __shfl_xor(lo, s, 16);
        hi += __shfl_xor(hi, s, 16);
    }

    int best = 0;
    int bestc = (int)(lo & 0xffull);
    #pragma unroll
    for (int b = 1; b < NB; ++b) {
        unsigned long long wsel = (b < 8) ? lo : hi;
        int c = (int)((wsel >> ((b & 7) * 8)) & 0xffull);
        if (c > bestc) { bestc = c; best = b; }
    }

    float sr = 0.f, sg = 0.f, sb = 0.f;
    #pragma unroll
    for (int t = 0; t < 8; ++t) {
        if (ci[t] == best) { sr += cr[t]; sg += cg[t]; sb += cb[t]; }
    }
    #pragma unroll
    for (int s = 1; s < 16; s <<= 1) {
        sr += __shfl_xor(sr, s, 16);
        sg += __shfl_xor(sg, s, 16);
        sb += __shfl_xor(sb, s, 16);
    }

    if (sub == 0 && valid) {
        float cm = (float)bestc;
        int o = wy * WO + wx;
        val[o]               = sr / cm;
        val[HO * WO + o]     = sg / cm;
        val[2 * HO * WO + o] = sb / cm;
    }
}

// Kernel 2 (band version): one block = (channel, by) band x-half.
// 11 output rows x ~1128 cols per block; lv loaded ONCE per band-half
// (vs once per row before: 11x fewer val reads, 11x fewer block ramps).
// Per-row alignment peel; aligned NT dwordx4 bulk stores (WRITE stays 61 MB).
__global__ __launch_bounds__(256) void write_kernel(const float* __restrict__ val,
                                                    float* __restrict__ out) {
    constexpr int XSEG = (OW + 1) / 2;     // 1128
    int band = blockIdx.y;                 // 0 .. 3*HO-1
    int c    = band / HO;
    int by   = band - c * HO;
    int xs   = blockIdx.x * XSEG;          // 0 or 1128
    int xe   = min(OW, xs + XSEG);

    __shared__ float lv[WO];
    if (threadIdx.x < WO) lv[threadIdx.x] = val[c * HO * WO + by * WO + threadIdx.x];
    __syncthreads();

    #pragma unroll
    for (int iy = 0; iy < PSP; ++iy) {
        bool zrow = (iy == PS);
        long rowbase = ((long)c * OH + (long)by * PSP + iy) * OW;
        long s0   = rowbase + xs;
        int  mis  = (int)(s0 & 3);
        int  lead = (4 - mis) & 3;
        int  span = xe - xs;
        int  n4   = (span - lead) >> 2;
        int  tail = span - lead - (n4 << 2);

        // head + tail scalars (<=6 elements)
        if (threadIdx.x < 8) {
            int e = threadIdx.x;
            int x = (e < lead) ? xs + e
                  : (e - lead < tail ? xs + lead + (n4 << 2) + (e - lead) : -1);
            if (x >= 0) {
                int bx = (int)((unsigned)x / (unsigned)PSP);
                int ix = x - bx * PSP;
                float v = (zrow || ix == PS) ? 0.0f : lv[bx];
                out[rowbase + x] = v;
            }
        }

        // aligned bulk: NT dwordx4
        for (int q = threadIdx.x; q < n4; q += 256) {
            int x0 = xs + lead + (q << 2);
            floatx4 vv;
            #pragma unroll
            for (int e = 0; e < 4; ++e) {
                int x  = x0 + e;
                int bx = (int)((unsigned)x / (unsigned)PSP);   // magic-mul
                int ix = x - bx * PSP;
                vv[e] = (zrow || ix == PS) ? 0.0f : lv[bx];
            }
            __builtin_nontemporal_store(vv, (floatx4*)(out + rowbase + x0));
        }
    }
}

extern "C" void kernel_launch(void* const* d_in, const int* in_sizes, int n_in,
                              void* d_out, int out_size, void* d_ws, size_t ws_size,
                              hipStream_t stream) {
    const float* rgb = (const float*)d_in[0];
    float* val = (float*)d_ws;         // 3*205*205 floats = 504,300 B scratch
    float* out = (float*)d_out;

    dim3 grid1((WO + TW - 1) / TW, (HO + TW - 1) / TW);   // 52 x 52 = 2704
    window_kernel<<<grid1, 256, 0, stream>>>(rgb, val);

    dim3 grid2(2, 3 * HO);                                // 1230 blocks
    write_kernel<<<grid2, 256, 0, stream>>>(val, out);
}

// Round 10
// 121.011 us; speedup vs baseline: 1.0237x; 1.0237x over previous
//
#include <hip/hip_runtime.h>

// Problem constants (nb=16, k=11, ps=10, with_padding=1, rgb 1x3x2048x2048 f32)
constexpr int H   = 2048;
constexpr int W   = 2048;
constexpr int NB  = 16;
constexpr int K   = 11;
constexpr int PS  = 10;
constexpr int PAD = (K - 1) / 2;                 // 5
constexpr int HO  = (H + 2 * PAD - K) / PS + 1;  // 205
constexpr int WO  = (W + 2 * PAD - K) / PS + 1;  // 205
constexpr int PSP = PS + 1;                      // 11
constexpr int OH  = HO * PSP;                    // 2255
constexpr int OW  = WO * PSP;                    // 2255

constexpr int TW  = 4;                       // 4x4 windows per block
constexpr int R   = (TW - 1) * PS + K;       // 41 rows needed
constexpr int NF4 = 11;                      // float4 slots/row: [gx0-3, gx0+41) covers cols 0..40
constexpr int LP  = NF4 * 4;                 // 44 floats LDS row pitch
constexpr int NSLOT = R * NF4;               // 451 float4 slots per channel (21.6 KB total)

typedef float floatx4 __attribute__((ext_vector_type(4)));

#if __has_builtin(__builtin_amdgcn_global_load_lds)
#define HAVE_GLL 1
typedef const __attribute__((address_space(1))) void* gas_ptr;
typedef __attribute__((address_space(3))) void* las_ptr;
#else
#define HAVE_GLL 0
#endif

// Integer binning, bit-equivalent to (int)(fl(fl(s/3))*0.0625f)  (proof R8).
__device__ __forceinline__ int bin_of(float s) {
    return (int)((unsigned)s / 48u);
}

// Kernel 1 (R8, best measured): one block = 4x4 window tile; GLL staging for
// interior blocks, float4+sentinel for edges; 16 threads/window; packed-u64
// histogram; shfl_xor(16) reduce; first-tie-wins argmax; conditional sums.
__global__ __launch_bounds__(256) void window_kernel(const float* __restrict__ rgb,
                                                     float* __restrict__ val) {
    __shared__ float ls_r[R * LP];
    __shared__ float ls_g[R * LP];
    __shared__ float ls_b[R * LP];

    int tid = threadIdx.x;
    int wy0 = blockIdx.y * TW;
    int wx0 = blockIdx.x * TW;
    int gy0 = wy0 * PS - PAD;
    int gx0 = wx0 * PS - PAD;          // == 3 (mod 4) for every block
    int f0  = gx0 >> 2;                // floor div: 10*bx - 2

    const float* __restrict__ rp = rgb;
    const float* __restrict__ gp = rgb + H * W;
    const float* __restrict__ bp = rgb + 2 * H * W;

    bool interior = (blockIdx.x >= 1) && (blockIdx.x <= 50) &&
                    (blockIdx.y >= 1) && (blockIdx.y <= 50);

#if HAVE_GLL
    if (interior) {
        int wv = tid >> 6;
        #pragma unroll
        for (int k = 0; k < 2; ++k) {
            int s     = k * 256 + tid;
            int sbase = k * 256 + wv * 64;
            if (sbase < NSLOT && s < NSLOT) {
                int row = s / NF4, f = s - row * NF4;
                long go = (long)(gy0 + row) * W + ((f0 + f) << 2);
                __builtin_amdgcn_global_load_lds((gas_ptr)(rp + go),
                                                 (las_ptr)(ls_r + sbase * 4), 16, 0, 0);
                __builtin_amdgcn_global_load_lds((gas_ptr)(gp + go),
                                                 (las_ptr)(ls_g + sbase * 4), 16, 0, 0);
                __builtin_amdgcn_global_load_lds((gas_ptr)(bp + go),
                                                 (las_ptr)(ls_b + sbase * 4), 16, 0, 0);
            }
        }
    } else
#endif
    {
        const float4 SENT = make_float4(1.0e9f, 1.0e9f, 1.0e9f, 1.0e9f);
        for (int s = tid; s < NSLOT; s += 256) {
            int row = s / NF4;
            int f   = s - row * NF4;
            int y   = gy0 + row;
            int fg  = f0 + f;
            float4 r4 = SENT, g4 = SENT, b4 = SENT;
            if ((unsigned)y < (unsigned)H && (unsigned)fg < (unsigned)(W / 4)) {
                long o = (long)y * W + (fg << 2);
                r4 = *(const float4*)(rp + o);
                g4 = *(const float4*)(gp + o);
                b4 = *(const float4*)(bp + o);
            }
            int la = row * LP + (f << 2);
            *(float4*)(ls_r + la) = r4;
            *(float4*)(ls_g + la) = g4;
            *(float4*)(ls_b + la) = b4;
        }
    }
    __syncthreads();

    int wid = tid >> 4;
    int sub = tid & 15;
    int wly = wid >> 2, wlx = wid & 3;
    int wy = wy0 + wly, wx = wx0 + wlx;
    bool valid = (wy < HO) && (wx < WO);
    int base = (wly * PS) * LP + (wlx * PS) + 3;

    float cr[8], cg[8], cb[8];
    int   ci[8];
    unsigned long long lo = 0ull, hi = 0ull;
    #pragma unroll
    for (int t = 0; t < 8; ++t) {
        int p = sub + 16 * t;
        float r = 0.f, g = 0.f, b = 0.f;
        int idx = 1 << 28;
        if (p < K * K) {
            int j = p / K, i = p - j * K;
            int addr = base + j * LP + i;
            r = ls_r[addr]; g = ls_g[addr]; b = ls_b[addr];
            idx = bin_of((r + g) + b);
        }
        cr[t] = r; cg[t] = g; cb[t] = b; ci[t] = idx;
        if ((unsigned)idx < 8u)       lo += 1ull << (idx * 8);
        else if ((unsigned)idx < 16u) hi += 1ull << ((idx - 8) * 8);
    }
    #pragma unroll
    for (int s = 1; s < 16; s <<= 1) {
        lo += __shfl_xor(lo, s, 16);
        hi += __shfl_xor(hi, s, 16);
    }

    int best = 0;
    int bestc = (int)(lo & 0xffull);
    #pragma unroll
    for (int b = 1; b < NB; ++b) {
        unsigned long long wsel = (b < 8) ? lo : hi;
        int c = (int)((wsel >> ((b & 7) * 8)) & 0xffull);
        if (c > bestc) { bestc = c; best = b; }
    }

    float sr = 0.f, sg = 0.f, sb = 0.f;
    #pragma unroll
    for (int t = 0; t < 8; ++t) {
        if (ci[t] == best) { sr += cr[t]; sg += cg[t]; sb += cb[t]; }
    }
    #pragma unroll
    for (int s = 1; s < 16; s <<= 1) {
        sr += __shfl_xor(sr, s, 16);
        sg += __shfl_xor(sg, s, 16);
        sb += __shfl_xor(sb, s, 16);
    }

    if (sub == 0 && valid) {
        float cm = (float)bestc;
        int o = wy * WO + wx;
        val[o]               = sr / cm;
        val[HO * WO + o]     = sg / cm;
        val[2 * HO * WO + o] = sb / cm;
    }
}

// Kernel 2 (reverted to R8 row-per-block — best measured): one block per
// output row; val row staged in LDS; aligned float4 nontemporal bulk stores +
// <=3-elem scalar head/tail. 6765 blocks (~26/CU) hide latency better than
// the R9 band version (4.8/CU).
__global__ __launch_bounds__(256) void write_kernel(const float* __restrict__ val,
                                                    float* __restrict__ out) {
    int row = blockIdx.x;              // 0 .. 3*OH-1
    int c   = row / OH;
    int y   = row - c * OH;
    int by  = y / PSP;
    int iy  = y - by * PSP;
    bool zrow = (iy == PS);

    __shared__ float lv[WO];
    if (threadIdx.x < WO)
        lv[threadIdx.x] = zrow ? 0.0f : val[c * HO * WO + by * WO + threadIdx.x];
    __syncthreads();

    long base = (long)row * OW;
    int  mis  = (int)(base & 3);
    int  lead = (4 - mis) & 3;
    int  n4   = (OW - lead) >> 2;
    int  tail = OW - lead - (n4 << 2);

    if (threadIdx.x < 8) {
        int e = threadIdx.x;
        int x = (e < lead) ? e : (e - lead < tail ? lead + (n4 << 2) + (e - lead) : -1);
        if (x >= 0) {
            int bx = (int)((unsigned)x / (unsigned)PSP);
            int ix = x - bx * PSP;
            float v = (zrow || ix == PS) ? 0.0f : lv[bx];
            out[base + x] = v;
        }
    }

    for (int q = threadIdx.x; q < n4; q += 256) {
        int x0 = lead + (q << 2);
        floatx4 vv;
        #pragma unroll
        for (int e = 0; e < 4; ++e) {
            int x  = x0 + e;
            int bx = (int)((unsigned)x / (unsigned)PSP);
            int ix = x - bx * PSP;
            vv[e] = (zrow || ix == PS) ? 0.0f : lv[bx];
        }
        __builtin_nontemporal_store(vv, (floatx4*)(out + base + x0));
    }
}

extern "C" void kernel_launch(void* const* d_in, const int* in_sizes, int n_in,
                              void* d_out, int out_size, void* d_ws, size_t ws_size,
                              hipStream_t stream) {
    const float* rgb = (const float*)d_in[0];
    float* val = (float*)d_ws;         // 3*205*205 floats = 504,300 B scratch
    float* out = (float*)d_out;

    dim3 grid1((WO + TW - 1) / TW, (HO + TW - 1) / TW);   // 52 x 52 = 2704
    window_kernel<<<grid1, 256, 0, stream>>>(rgb, val);

    write_kernel<<<3 * OH, 256, 0, stream>>>(val, out);   // 6765 blocks
}